// Round 1
// baseline (147.645 us; speedup 1.0000x reference)
//
#include <hip/hip_runtime.h>

#define NB    16
#define CIN   16
#define COUT  32
#define DIN   32
#define DOUT  30

typedef __attribute__((ext_vector_type(8)))  short        short8;
typedef __attribute__((ext_vector_type(4)))  unsigned int uint4v;
typedef __attribute__((ext_vector_type(16))) float        f32x16;

static __device__ __forceinline__ unsigned short f2bf_rne(float f) {
    unsigned int u = __builtin_bit_cast(unsigned int, f);
    u += 0x7fffu + ((u >> 16) & 1u);
    return (unsigned short)(u >> 16);
}
static __device__ __forceinline__ float bf2f(unsigned short s) {
    unsigned int u = ((unsigned int)s) << 16;
    return __builtin_bit_cast(float, u);
}
// packed f32x2 -> bf16x2 (RNE), src0 -> low half (std AMD pk convention)
static __device__ __forceinline__ unsigned int cvt_pk_bf16(float a, float b) {
    unsigned int r;
    asm("v_cvt_pk_bf16_f32 %0, %1, %2" : "=v"(r) : "v"(a), "v"(b));
    return r;
}

// Kernel 1: repack W[Cout][Cin][3][3][3] fp32 into MFMA A-fragment layout, bf16 hi/lo split.
// ws layout: hi: slice s (0..26) x lane (0..63) x 8 bf16 (16B chunks); lo at +1728 chunks.
// A-frag (32x32x16): lane l holds A[m=l&31][k=8*(l>>5)+j], m=co, k=ci.
__global__ __launch_bounds__(64) void repack_w(const float* __restrict__ wgt,
                                               short* __restrict__ ws) {
    const int s  = blockIdx.x;    // 0..26  (kd*9+kh*3+kw)
    const int l  = threadIdx.x;   // 0..63
    const int co  = l & 31;
    const int ci0 = (l >> 5) * 8;
    short8 vh, vl;
#pragma unroll
    for (int j = 0; j < 8; ++j) {
        float f = wgt[co * (CIN * 27) + (ci0 + j) * 27 + s];
        unsigned short h = f2bf_rne(f);
        vh[j] = (short)h;
        vl[j] = (short)f2bf_rne(f - bf2f(h));
    }
    ((short8*)ws)[s * 64 + l]            = vh;
    ((short8*)ws)[27 * 64 + s * 64 + l]  = vl;
}

// Main kernel: implicit-GEMM 3D conv + fused epilogue.
// Block = (htile, dpair, b): 8 waves (512 thr). Wave ww: wd=ww>>2 (d-plane), wy=ww&3 (h row).
// Computes output rows (b, :, d0+wd, h0+wy, 0..29) for all 32 co.
// LDS x-tile, bf16 hi/lo split: [part][dz 4][row 6][cichunk 2][w 32][ci8] shorts = 48 KB.
// B-frag ds_read_b128 is contiguous-by-lane (lane l -> byte l*16+kw*16): conflict-free.
__global__ __launch_bounds__(512) void conv3d_mfma(
    const float* __restrict__ x,
    const short* __restrict__ wsA,
    const float* __restrict__ cbias,
    const float* __restrict__ scal,
    const float* __restrict__ bpar,
    float* __restrict__ out)
{
    __shared__ __align__(16) short sx[2 * 12288];   // hi at 0, lo at +12288 shorts
    __shared__ float sp[96];

    const int htile = blockIdx.x;   // 0..7
    const int dpair = blockIdx.y;   // 0..14
    const int b     = blockIdx.z;   // 0..15

    const int tid  = threadIdx.x;
    const int ww   = tid >> 6;      // 0..7
    const int wd   = ww >> 2;       // 0..1
    const int wy   = ww & 3;        // 0..3
    const int lane = tid & 63;

    if (tid < 32) {
        sp[tid]      = cbias[tid];
        sp[32 + tid] = scal[tid];
        sp[64 + tid] = bpar[tid];
    }

    const int h0 = htile * 4;
    const int d0 = dpair * 2;

    // ---- stage x rows h0..h0+5, planes d0..d0+3, all 16 ci, into LDS (hi/lo bf16) ----
    // chunk c = ((dz*6+row)*2 + cichunk)*32 + w ; each chunk = 8 ci values (16B).
    const int xb = b * (CIN * DIN * DIN * DIN);
    for (int c = tid; c < 1536; c += 512) {
        const int w   = c & 31;
        const int hi8 = (c >> 5) & 1;
        const int rr  = c >> 6;         // dz*6+row, 0..23
        const int dz  = rr / 6;
        const int row = rr - dz * 6;
        int h_in = h0 + row; if (h_in > 31) h_in = 31;   // htile 7 halo clamp (rows unused)
        const int gbase = xb + (hi8 * 8) * (DIN * DIN * DIN)
                        + (d0 + dz) * (DIN * DIN) + h_in * DIN + w;
        float f[8];
#pragma unroll
        for (int j = 0; j < 8; ++j) f[j] = x[gbase + j * (DIN * DIN * DIN)];
        uint4v vh, vl;
#pragma unroll
        for (int j = 0; j < 8; j += 2) {
            unsigned int hp = cvt_pk_bf16(f[j], f[j + 1]);
            float b0 = __builtin_bit_cast(float, hp << 16);
            float b1 = __builtin_bit_cast(float, hp & 0xffff0000u);
            unsigned int lp = cvt_pk_bf16(f[j] - b0, f[j + 1] - b1);
            vh[j >> 1] = hp;
            vl[j >> 1] = lp;
        }
        const int idx = rr * 64 + hi8 * 32 + w;          // 16B units
        *(uint4v*)(sx + idx * 8)             = vh;
        *(uint4v*)(sx + 12288 + idx * 8)     = vl;
    }
    __syncthreads();

    const int h = h0 + wy;
    if (h >= DOUT) return;    // only barrier above; safe to exit
    const int d = d0 + wd;    // output d-plane, <= 29 always valid

    const int n  = lane & 31;   // output w (30 valid + 2 pad)
    const int hi = lane >> 5;

    // per-lane LDS offsets (shorts): cichunk select by hi, then w slot
    int wofs[3];
#pragma unroll
    for (int kw = 0; kw < 3; ++kw) {
        int wc = n + kw; if (wc > 31) wc = 31;   // pad lanes clamp (cols >=30 discarded)
        wofs[kw] = hi * 256 + wc * 8;
    }

    f32x16 acc;
#pragma unroll
    for (int i = 0; i < 16; ++i) acc[i] = 0.0f;

    const short8* wa = (const short8*)wsA;
#pragma unroll
    for (int kd = 0; kd < 3; ++kd) {
#pragma unroll
        for (int kh = 0; kh < 3; ++kh) {
            const int rbase = ((wd + kd) * 6 + wy + kh) * 512;   // shorts
#pragma unroll
            for (int kw = 0; kw < 3; ++kw) {
                const int s = kd * 9 + kh * 3 + kw;
                short8 ah = wa[s * 64 + lane];
                short8 al = wa[1728 + s * 64 + lane];
                short8 bh = *(const short8*)(sx + rbase + wofs[kw]);
                short8 bl = *(const short8*)(sx + 12288 + rbase + wofs[kw]);
                acc = __builtin_amdgcn_mfma_f32_32x32x16_bf16(ah, bh, acc, 0, 0, 0);
                acc = __builtin_amdgcn_mfma_f32_32x32x16_bf16(ah, bl, acc, 0, 0, 0);
                acc = __builtin_amdgcn_mfma_f32_32x32x16_bf16(al, bh, acc, 0, 0, 0);
            }
        }
    }

    // ---- epilogue: bias, tanh*scale, *bp, sigmoid; C/D map: co=(r&3)+8*(r>>2)+4*hi, col=n ----
    if (n < DOUT) {
        const int obase = b * (COUT * DOUT * DOUT * DOUT)
                        + d * (DOUT * DOUT) + h * DOUT + n;
#pragma unroll
        for (int r = 0; r < 16; ++r) {
            const int co = (r & 3) + 8 * (r >> 2) + 4 * hi;
            float y  = acc[r] + sp[co];
            float t  = y * sp[32 + co];
            float th = 1.0f - 2.0f / (__expf(2.0f * t) + 1.0f);
            float z  = th * sp[64 + co];
            float rr = 1.0f / (1.0f + __expf(-z));
            out[obase + co * (DOUT * DOUT * DOUT)] = rr;
        }
    }
}

extern "C" void kernel_launch(void* const* d_in, const int* in_sizes, int n_in,
                              void* d_out, int out_size, void* d_ws, size_t ws_size,
                              hipStream_t stream) {
    const float* x     = (const float*)d_in[0];
    const float* wgt   = (const float*)d_in[1];
    const float* cbias = (const float*)d_in[2];
    const float* scal  = (const float*)d_in[3];
    const float* bpar  = (const float*)d_in[4];
    float* out = (float*)d_out;
    short* ws  = (short*)d_ws;   // 27*64*16B * 2 = 55296 bytes used

    hipLaunchKernelGGL(repack_w, dim3(27), dim3(64), 0, stream, wgt, ws);
    hipLaunchKernelGGL(conv3d_mfma, dim3(8, 15, NB), dim3(512), 0, stream,
                       x, ws, cbias, scal, bpar, out);
}